// Round 17
// baseline (307.967 us; speedup 1.0000x reference)
//
#include <hip/hip_runtime.h>

// LIF layer: B=64, T=256, P=1024, D=1024. reference ignores prv_voltage.
// d_out = [voltage (B*T*D fp32) | spikes (B*T*D fp32)].
//
// NUMERICS LOCKED (R10): currents[row,d] =
//   (asc-p f32 single-acc sum over active p in [0,512))
// + (asc-p f32 single-acc sum over active p in [512,1024)), f32;
// scan = f32 separate mul-then-add, >=1.0, reset-to-zero.
//
// R17 = R16's K1 (nt spikes-load + nt currents-store: keeps W L2-resident,
// FETCH 213->106MB, K1 280->266us) + R12's PLAIN K2 (cached loads/stores).
// R16's all-nt K2 regressed ~40us: nt loads bypass L2 (no allocation, full
// HBM latency each) and the 4-deep prefetch can't hide it. K2's currents
// reads are stream-once but benefit from normal caching + coalescing.

#define LIF_B 64
#define LIF_T 256
#define LIF_P 1024
#define LIF_D 1024
#define LIF_N ((size_t)LIF_B * LIF_T * LIF_D)

typedef float f32x4 __attribute__((ext_vector_type(4)));

__global__ __launch_bounds__(256) void lif_currents_kernel(
    const float* __restrict__ spikes,   // (B*T, P)
    const float* __restrict__ W,        // (P, D)
    float* __restrict__ cur_out)        // (B*T, D) — voltage region of d_out
{
    __shared__ unsigned long long smask[16];
    __shared__ int plist[1024];          // panel0 at [0..c0), panel1 at [512..512+c1)
    __shared__ int scnt[2];

    const int row  = blockIdx.x;          // 0 .. B*T-1
    const int tid  = threadIdx.x;
    const int lane = tid & 63;
    const int wave = tid >> 6;            // 4 waves x 256 d-columns
    const int dbase = wave << 8;

    const float* srow = spikes + (size_t)row * LIF_P;
    const float* wcol = W + dbase + (lane << 2);   // this lane's 4 columns

    // Phase 1: cooperative mask build — wave w handles chunks 4w..4w+3.
    // spikes are streaming (read once): non-temporal, don't evict W from L2.
    for (int jj = 0; jj < 4; ++jj) {
        const int j = (wave << 2) + jj;
        const float sv = __builtin_nontemporal_load(&srow[(j << 6) + lane]);
        const unsigned long long m = __ballot(sv != 0.0f);
        if (lane == 0) smask[j] = m;
    }
    __syncthreads();

    // Phase 2: wave 0, lanes 0..15 build ascending p-lists (one chunk each).
    if (wave == 0) {
        unsigned long long m = (lane < 16) ? smask[lane] : 0ULL;
        const int pc = __popcll(m);
        int s = pc;                       // inclusive prefix within 8-lane group
        for (int d = 1; d < 8; d <<= 1) {
            const int vps = __shfl_up(s, d, 8);
            if ((lane & 7) >= d) s += vps;
        }
        if (lane == 7)  scnt[0] = s;
        if (lane == 15) scnt[1] = s;
        if (lane < 16) {
            int idx = ((lane < 8) ? 0 : 512) + (s - pc);
            const int pb = lane << 6;
            while (m) {
                plist[idx++] = pb + __builtin_ctzll(m);
                m &= (m - 1);
            }
        }
    }
    __syncthreads();

    const int c0 = scnt[0];
    const int c1 = scnt[1];

    float a0x=0.f,a0y=0.f,a0z=0.f,a0w=0.f;
    float a1x=0.f,a1y=0.f,a1z=0.f,a1w=0.f;

    #define LIF_ACC(AX,AY,AZ,AW,WV)                                             \
        AX = __fadd_rn(AX, (WV).x); AY = __fadd_rn(AY, (WV).y);                  \
        AZ = __fadd_rn(AZ, (WV).z); AW = __fadd_rn(AW, (WV).w);

    #define LIF_PANEL(BASE, CNT, AX,AY,AZ,AW)                                    \
    {                                                                            \
        int i = 0;                                                               \
        for (; i + 4 <= (CNT); i += 4) {                                         \
            const int4 ps = *reinterpret_cast<const int4*>(&plist[(BASE) + i]);  \
            const float4 w0 = *reinterpret_cast<const float4*>(wcol + ((size_t)ps.x << 10)); \
            const float4 w1 = *reinterpret_cast<const float4*>(wcol + ((size_t)ps.y << 10)); \
            const float4 w2 = *reinterpret_cast<const float4*>(wcol + ((size_t)ps.z << 10)); \
            const float4 w3 = *reinterpret_cast<const float4*>(wcol + ((size_t)ps.w << 10)); \
            LIF_ACC(AX,AY,AZ,AW, w0) LIF_ACC(AX,AY,AZ,AW, w1)                    \
            LIF_ACC(AX,AY,AZ,AW, w2) LIF_ACC(AX,AY,AZ,AW, w3)                    \
        }                                                                        \
        for (; i < (CNT); ++i) {                                                 \
            const int p = plist[(BASE) + i];                                     \
            const float4 wv = *reinterpret_cast<const float4*>(wcol + ((size_t)p << 10)); \
            LIF_ACC(AX,AY,AZ,AW, wv)                                             \
        }                                                                        \
    }

    LIF_PANEL(0,   c0, a0x,a0y,a0z,a0w)   // p in [0, 512), ascending
    LIF_PANEL(512, c1, a1x,a1y,a1z,a1w)   // p in [512, 1024), ascending
    #undef LIF_PANEL
    #undef LIF_ACC

    // Panel association: P0 + P1, plain f32 add (locked).
    f32x4 c;
    c.x = __fadd_rn(a0x, a1x);
    c.y = __fadd_rn(a0y, a1y);
    c.z = __fadd_rn(a0z, a1z);
    c.w = __fadd_rn(a0w, a1w);

    // currents store is streaming: non-temporal (keeps W resident in L2).
    __builtin_nontemporal_store(
        c, reinterpret_cast<f32x4*>(cur_out + (size_t)row * LIF_D + dbase + (lane << 2)));
}

__global__ __launch_bounds__(256) void lif_scan_kernel(
    float* __restrict__ voltage,        // in: staged currents, out: v_new
    float* __restrict__ spikes_out)     // out: binary spikes
{
    const int tid = blockIdx.x * 256 + threadIdx.x;   // 0 .. B*D-1
    const int b = tid >> 10;
    const int d = tid & (LIF_D - 1);

    float v = 0.0f;
    const size_t base = ((size_t)b * LIF_T) * LIF_D + d;

    // 4-deep prefetch: current loads don't depend on the serial v chain.
    float p0 = voltage[base + 0*(size_t)LIF_D];
    float p1 = voltage[base + 1*(size_t)LIF_D];
    float p2 = voltage[base + 2*(size_t)LIF_D];
    float p3 = voltage[base + 3*(size_t)LIF_D];

    for (int t = 0; t < LIF_T; t += 4) {
        const float c0 = p0, c1 = p1, c2 = p2, c3 = p3;
        if (t + 4 < LIF_T) {
            p0 = voltage[base + (size_t)(t + 4) * LIF_D];
            p1 = voltage[base + (size_t)(t + 5) * LIF_D];
            p2 = voltage[base + (size_t)(t + 6) * LIF_D];
            p3 = voltage[base + (size_t)(t + 7) * LIF_D];
        }
        const size_t i0 = base + (size_t)t * LIF_D;
        // numpy scan: separate f32 mul then add (no FMA contraction) — locked.
        {
            const float vn = __fadd_rn(__fmul_rn(0.9f, v), c0);
            const bool f = (vn >= 1.0f);
            voltage[i0 + 0*(size_t)LIF_D] = vn;
            spikes_out[i0 + 0*(size_t)LIF_D] = f ? 1.0f : 0.0f;
            v = f ? 0.0f : vn;
        }
        {
            const float vn = __fadd_rn(__fmul_rn(0.9f, v), c1);
            const bool f = (vn >= 1.0f);
            voltage[i0 + 1*(size_t)LIF_D] = vn;
            spikes_out[i0 + 1*(size_t)LIF_D] = f ? 1.0f : 0.0f;
            v = f ? 0.0f : vn;
        }
        {
            const float vn = __fadd_rn(__fmul_rn(0.9f, v), c2);
            const bool f = (vn >= 1.0f);
            voltage[i0 + 2*(size_t)LIF_D] = vn;
            spikes_out[i0 + 2*(size_t)LIF_D] = f ? 1.0f : 0.0f;
            v = f ? 0.0f : vn;
        }
        {
            const float vn = __fadd_rn(__fmul_rn(0.9f, v), c3);
            const bool f = (vn >= 1.0f);
            voltage[i0 + 3*(size_t)LIF_D] = vn;
            spikes_out[i0 + 3*(size_t)LIF_D] = f ? 1.0f : 0.0f;
            v = f ? 0.0f : vn;
        }
    }
}

extern "C" void kernel_launch(void* const* d_in, const int* in_sizes, int n_in,
                              void* d_out, int out_size, void* d_ws, size_t ws_size,
                              hipStream_t stream) {
    (void)in_sizes; (void)n_in; (void)out_size; (void)d_ws; (void)ws_size;

    // d_in[0] = prv_voltage (UNUSED by reference)
    const float* spikes = (const float*)d_in[1];   // (B,T,P) binary fp32
    const float* W      = (const float*)d_in[2];   // (P,D) fp32

    float* out        = (float*)d_out;
    float* voltage    = out;                       // N floats (stages currents)
    float* spikes_out = out + LIF_N;               // N floats

    lif_currents_kernel<<<LIF_B * LIF_T, 256, 0, stream>>>(spikes, W, voltage);
    lif_scan_kernel<<<(LIF_B * LIF_D) / 256, 256, 0, stream>>>(voltage, spikes_out);
}

// Round 18
// 290.617 us; speedup vs baseline: 1.0597x; 1.0597x over previous
//
#include <hip/hip_runtime.h>

// LIF layer: B=64, T=256, P=1024, D=1024. reference ignores prv_voltage.
// d_out = [voltage (B*T*D fp32) | spikes (B*T*D fp32)].
//
// NUMERICS LOCKED (R10): currents[row,d] =
//   (asc-p f32 single-acc sum over active p in [0,512))
// + (asc-p f32 single-acc sum over active p in [512,1024)), f32;
// scan = f32 separate mul-then-add, >=1.0, reset-to-zero.
//
// R18 = R12 base + (a) nt ONLY on the spikes input stream (halves W-evicting
// L2 traffic; R16/17 proved the mechanism but nt on currents-store broke L3
// forwarding to K2, +40us) + (b) 8-wide plist batches (R11's 8-wide failure
// was duplicate loads + cndmask, both absent here: distinct ascending
// indices, unconditional in-order adds).
// K2 = R12's plain cached version (reads currents from L3, ~35us).

#define LIF_B 64
#define LIF_T 256
#define LIF_P 1024
#define LIF_D 1024
#define LIF_N ((size_t)LIF_B * LIF_T * LIF_D)

__global__ __launch_bounds__(256) void lif_currents_kernel(
    const float* __restrict__ spikes,   // (B*T, P)
    const float* __restrict__ W,        // (P, D)
    float* __restrict__ cur_out)        // (B*T, D) — voltage region of d_out
{
    __shared__ unsigned long long smask[16];
    __shared__ int plist[1024];          // panel0 at [0..c0), panel1 at [512..512+c1)
    __shared__ int scnt[2];

    const int row  = blockIdx.x;          // 0 .. B*T-1
    const int tid  = threadIdx.x;
    const int lane = tid & 63;
    const int wave = tid >> 6;            // 4 waves x 256 d-columns
    const int dbase = wave << 8;

    const float* srow = spikes + (size_t)row * LIF_P;
    const float* wcol = W + dbase + (lane << 2);   // this lane's 4 columns

    // Phase 1: mask build; spikes = pure input stream -> nt (protect W in L2).
    for (int jj = 0; jj < 4; ++jj) {
        const int j = (wave << 2) + jj;
        const float sv = __builtin_nontemporal_load(&srow[(j << 6) + lane]);
        const unsigned long long m = __ballot(sv != 0.0f);
        if (lane == 0) smask[j] = m;
    }
    __syncthreads();

    // Phase 2: wave 0, lanes 0..15 build ascending p-lists (one chunk each).
    if (wave == 0) {
        unsigned long long m = (lane < 16) ? smask[lane] : 0ULL;
        const int pc = __popcll(m);
        int s = pc;                       // inclusive prefix within 8-lane group
        for (int d = 1; d < 8; d <<= 1) {
            const int vps = __shfl_up(s, d, 8);
            if ((lane & 7) >= d) s += vps;
        }
        if (lane == 7)  scnt[0] = s;
        if (lane == 15) scnt[1] = s;
        if (lane < 16) {
            int idx = ((lane < 8) ? 0 : 512) + (s - pc);
            const int pb = lane << 6;
            while (m) {
                plist[idx++] = pb + __builtin_ctzll(m);
                m &= (m - 1);
            }
        }
    }
    __syncthreads();

    const int c0 = scnt[0];
    const int c1 = scnt[1];

    float a0x=0.f,a0y=0.f,a0z=0.f,a0w=0.f;
    float a1x=0.f,a1y=0.f,a1z=0.f,a1w=0.f;

    #define LIF_ACC(AX,AY,AZ,AW,WV)                                             \
        AX = __fadd_rn(AX, (WV).x); AY = __fadd_rn(AY, (WV).y);                  \
        AZ = __fadd_rn(AZ, (WV).z); AW = __fadd_rn(AW, (WV).w);

    #define LIF_PANEL(BASE, CNT, AX,AY,AZ,AW)                                    \
    {                                                                            \
        int i = 0;                                                               \
        for (; i + 8 <= (CNT); i += 8) {                                         \
            const int4 pa = *reinterpret_cast<const int4*>(&plist[(BASE) + i]);      \
            const int4 pb = *reinterpret_cast<const int4*>(&plist[(BASE) + i + 4]);  \
            const float4 w0 = *reinterpret_cast<const float4*>(wcol + ((size_t)pa.x << 10)); \
            const float4 w1 = *reinterpret_cast<const float4*>(wcol + ((size_t)pa.y << 10)); \
            const float4 w2 = *reinterpret_cast<const float4*>(wcol + ((size_t)pa.z << 10)); \
            const float4 w3 = *reinterpret_cast<const float4*>(wcol + ((size_t)pa.w << 10)); \
            const float4 w4 = *reinterpret_cast<const float4*>(wcol + ((size_t)pb.x << 10)); \
            const float4 w5 = *reinterpret_cast<const float4*>(wcol + ((size_t)pb.y << 10)); \
            const float4 w6 = *reinterpret_cast<const float4*>(wcol + ((size_t)pb.z << 10)); \
            const float4 w7 = *reinterpret_cast<const float4*>(wcol + ((size_t)pb.w << 10)); \
            LIF_ACC(AX,AY,AZ,AW, w0) LIF_ACC(AX,AY,AZ,AW, w1)                    \
            LIF_ACC(AX,AY,AZ,AW, w2) LIF_ACC(AX,AY,AZ,AW, w3)                    \
            LIF_ACC(AX,AY,AZ,AW, w4) LIF_ACC(AX,AY,AZ,AW, w5)                    \
            LIF_ACC(AX,AY,AZ,AW, w6) LIF_ACC(AX,AY,AZ,AW, w7)                    \
        }                                                                        \
        for (; i + 4 <= (CNT); i += 4) {                                         \
            const int4 ps = *reinterpret_cast<const int4*>(&plist[(BASE) + i]);  \
            const float4 w0 = *reinterpret_cast<const float4*>(wcol + ((size_t)ps.x << 10)); \
            const float4 w1 = *reinterpret_cast<const float4*>(wcol + ((size_t)ps.y << 10)); \
            const float4 w2 = *reinterpret_cast<const float4*>(wcol + ((size_t)ps.z << 10)); \
            const float4 w3 = *reinterpret_cast<const float4*>(wcol + ((size_t)ps.w << 10)); \
            LIF_ACC(AX,AY,AZ,AW, w0) LIF_ACC(AX,AY,AZ,AW, w1)                    \
            LIF_ACC(AX,AY,AZ,AW, w2) LIF_ACC(AX,AY,AZ,AW, w3)                    \
        }                                                                        \
        for (; i < (CNT); ++i) {                                                 \
            const int p = plist[(BASE) + i];                                     \
            const float4 wv = *reinterpret_cast<const float4*>(wcol + ((size_t)p << 10)); \
            LIF_ACC(AX,AY,AZ,AW, wv)                                             \
        }                                                                        \
    }

    LIF_PANEL(0,   c0, a0x,a0y,a0z,a0w)   // p in [0, 512), ascending
    LIF_PANEL(512, c1, a1x,a1y,a1z,a1w)   // p in [512, 1024), ascending
    #undef LIF_PANEL
    #undef LIF_ACC

    // Panel association: P0 + P1, plain f32 add (locked).
    float4 c;
    c.x = __fadd_rn(a0x, a1x);
    c.y = __fadd_rn(a0y, a1y);
    c.z = __fadd_rn(a0z, a1z);
    c.w = __fadd_rn(a0w, a1w);

    // cached store: K2 reads currents from L2/L3 (nt here cost +40us, R17).
    *reinterpret_cast<float4*>(cur_out + (size_t)row * LIF_D + dbase + (lane << 2)) = c;
}

__global__ __launch_bounds__(256) void lif_scan_kernel(
    float* __restrict__ voltage,        // in: staged currents, out: v_new
    float* __restrict__ spikes_out)     // out: binary spikes
{
    const int tid = blockIdx.x * 256 + threadIdx.x;   // 0 .. B*D-1
    const int b = tid >> 10;
    const int d = tid & (LIF_D - 1);

    float v = 0.0f;
    const size_t base = ((size_t)b * LIF_T) * LIF_D + d;

    // 4-deep prefetch: current loads don't depend on the serial v chain.
    float p0 = voltage[base + 0*(size_t)LIF_D];
    float p1 = voltage[base + 1*(size_t)LIF_D];
    float p2 = voltage[base + 2*(size_t)LIF_D];
    float p3 = voltage[base + 3*(size_t)LIF_D];

    for (int t = 0; t < LIF_T; t += 4) {
        const float c0 = p0, c1 = p1, c2 = p2, c3 = p3;
        if (t + 4 < LIF_T) {
            p0 = voltage[base + (size_t)(t + 4) * LIF_D];
            p1 = voltage[base + (size_t)(t + 5) * LIF_D];
            p2 = voltage[base + (size_t)(t + 6) * LIF_D];
            p3 = voltage[base + (size_t)(t + 7) * LIF_D];
        }
        const size_t i0 = base + (size_t)t * LIF_D;
        // numpy scan: separate f32 mul then add (no FMA contraction) — locked.
        {
            const float vn = __fadd_rn(__fmul_rn(0.9f, v), c0);
            const bool f = (vn >= 1.0f);
            voltage[i0 + 0*(size_t)LIF_D] = vn;
            spikes_out[i0 + 0*(size_t)LIF_D] = f ? 1.0f : 0.0f;
            v = f ? 0.0f : vn;
        }
        {
            const float vn = __fadd_rn(__fmul_rn(0.9f, v), c1);
            const bool f = (vn >= 1.0f);
            voltage[i0 + 1*(size_t)LIF_D] = vn;
            spikes_out[i0 + 1*(size_t)LIF_D] = f ? 1.0f : 0.0f;
            v = f ? 0.0f : vn;
        }
        {
            const float vn = __fadd_rn(__fmul_rn(0.9f, v), c2);
            const bool f = (vn >= 1.0f);
            voltage[i0 + 2*(size_t)LIF_D] = vn;
            spikes_out[i0 + 2*(size_t)LIF_D] = f ? 1.0f : 0.0f;
            v = f ? 0.0f : vn;
        }
        {
            const float vn = __fadd_rn(__fmul_rn(0.9f, v), c3);
            const bool f = (vn >= 1.0f);
            voltage[i0 + 3*(size_t)LIF_D] = vn;
            spikes_out[i0 + 3*(size_t)LIF_D] = f ? 1.0f : 0.0f;
            v = f ? 0.0f : vn;
        }
    }
}

extern "C" void kernel_launch(void* const* d_in, const int* in_sizes, int n_in,
                              void* d_out, int out_size, void* d_ws, size_t ws_size,
                              hipStream_t stream) {
    (void)in_sizes; (void)n_in; (void)out_size; (void)d_ws; (void)ws_size;

    // d_in[0] = prv_voltage (UNUSED by reference)
    const float* spikes = (const float*)d_in[1];   // (B,T,P) binary fp32
    const float* W      = (const float*)d_in[2];   // (P,D) fp32

    float* out        = (float*)d_out;
    float* voltage    = out;                       // N floats (stages currents)
    float* spikes_out = out + LIF_N;               // N floats

    lif_currents_kernel<<<LIF_B * LIF_T, 256, 0, stream>>>(spikes, W, voltage);
    lif_scan_kernel<<<(LIF_B * LIF_D) / 256, 256, 0, stream>>>(voltage, spikes_out);
}